// Round 13
// baseline (200.466 us; speedup 1.0000x reference)
//
#include <hip/hip_runtime.h>
#include <hip/hip_bf16.h>
#include <math.h>

#define SEQ_LEN 128
#define BATCH   32
#define T       32
#define TT      (T*T)     // 1024
#define TTT     (T*T*T)   // 32768
#define START   30
#define END     31
#define NGEN    63
#define TSTR    36        // tile row stride (words): rows 16B-aligned, conflict-free

#define LOG2E   1.44269504088896f
#define OFF4    5.77078016355587f   // 4 * log2(e)

typedef unsigned long long u64;

__device__ __forceinline__ u64 pt_pack(int tag, float v) {
    union { float f; unsigned int u; } c; c.f = v;
    return ((u64)(unsigned int)tag << 32) | (u64)c.u;
}
__device__ __forceinline__ float pt_val(u64 w) {
    union { unsigned int u; float f; } c; c.u = (unsigned int)w; return c.f;
}
__device__ __forceinline__ int pt_tag(u64 w) { return (int)(w >> 32); }

__device__ __forceinline__ u64 ald64(const u64* p) {
    return __hip_atomic_load(p, __ATOMIC_RELAXED, __HIP_MEMORY_SCOPE_AGENT);
}
__device__ __forceinline__ void ast64(u64* p, u64 v) {
    __hip_atomic_store(p, v, __ATOMIC_RELAXED, __HIP_MEMORY_SCOPE_AGENT);
}

#define LGKM0_FENCE() do {                                  \
    asm volatile("s_waitcnt lgkmcnt(0)" ::: "memory");      \
    __builtin_amdgcn_sched_barrier(0);                      \
} while (0)

// ---------------------------------------------------------------------------
// Kernel 1: tg_energy gather. ws[0..15] <- per-block partial sums.
// ---------------------------------------------------------------------------
__global__ __launch_bounds__(256) void tg_kernel(const float* __restrict__ scores,
                                                 const int*   __restrict__ target,
                                                 const int*   __restrict__ mask,
                                                 float*       __restrict__ ws) {
    int idx = blockIdx.x * 256 + threadIdx.x;
    float v = 0.0f;
    if (mask[idx] != 0) v = scores[(size_t)idx * TTT + target[idx]];
    #pragma unroll
    for (int off = 32; off > 0; off >>= 1) v += __shfl_down(v, off, 64);
    __shared__ float partial[4];
    int wave = threadIdx.x >> 6, lane = threadIdx.x & 63;
    if (lane == 0) partial[wave] = v;
    __syncthreads();
    if (threadIdx.x == 0)
        ws[blockIdx.x] = partial[0] + partial[1] + partial[2] + partial[3];
}

// ---------------------------------------------------------------------------
// Kernel 2: init tagged buffers (full overwrite each launch: replay-safe).
// ptF[b]: parity1 <- Q_1 (tag 1) at word j*32+i; parity0 <- 0.
// ptB[b]: parity0 <- R_127 (tag 128, indicator at END*32+END); parity1 <- 0.
// ---------------------------------------------------------------------------
__global__ __launch_bounds__(256) void init_dfb(const float* __restrict__ scores,
                                                u64* __restrict__ ptF,
                                                u64* __restrict__ ptB) {
    const int blk = blockIdx.x, tid = threadIdx.x;
    if (blk < BATCH) {
        const int b = blk;
        u64* pt = ptF + (size_t)b * 2048;
        #pragma unroll
        for (int q = 0; q < 4; ++q) {
            int e = q * 256 + tid;           // e = j*32 + i
            int i = e & 31, j = e >> 5;
            float p1 = scores[(size_t)(0*BATCH + b)*TTT + START*TT + START*T + i];
            float s1 = scores[(size_t)(1*BATCH + b)*TTT + START*TT + i*T + j];
            pt[1024 + e] = pt_pack(1, __expf(p1 + s1));
            pt[e]        = 0ULL;
        }
    } else {
        const int b = blk - BATCH;
        u64* pt = ptB + (size_t)b * 2048;
        #pragma unroll
        for (int q = 0; q < 4; ++q) {
            int e = q * 256 + tid;           // e = i*32 + j
            float v = (e == END*T + END) ? 1.0f : 0.0f;
            pt[e]        = pt_pack(128, v);
            pt[1024 + e] = 0ULL;
        }
    }
}

// ---------------------------------------------------------------------------
// Kernel 3: wave0-autonomous distributed fwd/bwd scan. 512 blocks x 512 thr.
// g=bid&7, chain=bid>>3, b=chain&31, dirB=chain>=32.
// Waves 1..7: staging. Load tile (1024 float4s = 32 i x 128 run), apply
//   exp2(s*log2e-4log2e), scatter into 4-deep LDS ring (rows = output index,
//   stride 36, 16B-aligned). Handshake: readyCtr += 1 per wave per gen
//   (after lgkmcnt drain); wait doneGen >= gen-4 before slot overwrite.
// Wave0: the entire critical path, NO barriers:
//   poll own 128-word range (r8 protocol: all 128 tag-checked before any
//   publish -> certification proof unchanged) -> pldL via wave-local LDS
//   (lgkmcnt fence only) -> 2 outputs/lane, 32 FMA each (exp pre-applied)
//   -> publish 2 owned words -> bump doneGen.
// Masked steps: poll (certification), republish register-cached values.
// ---------------------------------------------------------------------------
__global__ __launch_bounds__(512, 4) void scan_w0(const float* __restrict__ scores,
                                                  const int*   __restrict__ maskI,
                                                  u64*         __restrict__ ptF,
                                                  u64*         __restrict__ ptB) {
    const int bid   = blockIdx.x;
    const int g     = bid & 7;
    const int chain = bid >> 3;
    const int b     = chain & 31;
    const bool dirB = (chain >> 5) != 0;
    const int tid   = threadIdx.x;
    const int lane  = tid & 63;

    __shared__ __align__(16) float sm[4][128 * TSTR];   // 73.7 KB ring
    __shared__ float pldL[128];
    __shared__ int readyCtr;
    __shared__ int doneGen;

    // mask as wave-uniform bitfields
    const u64 mlo = __ballot(maskI[lane * BATCH + b] != 0);
    const u64 mhi = __ballot(maskI[(64 + lane) * BATCH + b] != 0);
    auto act_of = [&](int t) {
        return (((t < 64) ? (mlo >> t) : (mhi >> (t - 64))) & 1ULL) != 0ULL;
    };

    if (tid == 0) { readyCtr = 0; doneGen = -1; }
    __syncthreads();

    u64* const pt = (dirB ? ptB : ptF) + (size_t)b * 2048;
    auto sb = [&](int t) { return scores + ((size_t)t * BATCH + b) * TTT; };

    if (tid >= 64) {
        // ------------------------- staging waves 1..7 -------------------------
        const int u = tid - 64;                 // 0..447
        for (int gen = 0; gen < NGEN; ++gen) {
            const int t = dirB ? (127 - gen) : (2 + gen);
            if (gen >= 4) {
                while (__hip_atomic_load(&doneGen, __ATOMIC_RELAXED,
                                         __HIP_MEMORY_SCOPE_WORKGROUP) < gen - 4) {}
                asm volatile("" ::: "memory");
                __builtin_amdgcn_sched_barrier(0);
            }
            const int buf = gen & 3;
            if (act_of(t)) {
                const float* base = sb(t);
                // tile = 32 (i) x 128 (run) floats = 1024 float4s
                for (int p = u; p < 1024; p += 448) {
                    const int i = p >> 5;       // 0..31
                    const int c = p & 31;       // float4-chunk within the run
                    float4 v = *(const float4*)(base + (size_t)i * TT + g * 128 + c * 4);
                    v.x = exp2f(fmaf(v.x, LOG2E, -OFF4));
                    v.y = exp2f(fmaf(v.y, LOG2E, -OFF4));
                    v.z = exp2f(fmaf(v.z, LOG2E, -OFF4));
                    v.w = exp2f(fmaf(v.w, LOG2E, -OFF4));
                    if (!dirB) {
                        // row = run-pos (jj*32+k) = c*4+q, col = i
                        const int r0 = c * 4;
                        sm[buf][(r0 + 0) * TSTR + i] = v.x;
                        sm[buf][(r0 + 1) * TSTR + i] = v.y;
                        sm[buf][(r0 + 2) * TSTR + i] = v.z;
                        sm[buf][(r0 + 3) * TSTR + i] = v.w;
                    } else {
                        // row = i*4 + jj, col = k (4 consecutive, 16B aligned)
                        const int row = i * 4 + (c >> 3);
                        const int col = (c & 7) * 4;
                        *(float4*)&sm[buf][row * TSTR + col] = v;
                    }
                }
            }
            LGKM0_FENCE();   // drain this wave's LDS writes before signalling
            if (lane == 0)
                __hip_atomic_fetch_add(&readyCtr, 1, __ATOMIC_RELAXED,
                                       __HIP_MEMORY_SCOPE_WORKGROUP);
        }
    } else {
        // ------------------------- wave0: the chain -------------------------
        const int o0 = lane, o1 = lane + 64;     // owned output indices
        int w0own, w1own, p0off, p1off;
        if (!dirB) {
            const int k = lane & 31;
            const int jj0 = lane >> 5, jj1 = 2 + (lane >> 5);
            w0own = k * 32 + 4 * g + jj0;        // o0 = jj0*32+k row
            w1own = k * 32 + 4 * g + jj1;        // o1 = jj1*32+k row
            p0off = jj0 * 32; p1off = jj1 * 32;
        } else {
            w0own = (o0 >> 2) * 32 + 4 * g + (o0 & 3);   // o = i*4+jj
            w1own = (o1 >> 2) * 32 + 4 * g + (o1 & 3);
            p0off = (o0 & 3) * 32; p1off = (o1 & 3) * 32;
        }
        const int parInit = dirB ? 0 : 1;
        float last0 = pt_val(pt[parInit * 1024 + w0own]);
        float last1 = pt_val(pt[parInit * 1024 + w1own]);

        for (int gen = 0; gen < NGEN; ++gen) {
            const int t    = dirB ? (127 - gen) : (2 + gen);
            const bool act = act_of(t);
            const int buf  = gen & 3;
            const int tagw = dirB ? (t + 1) : (t - 1);
            const int spar = dirB ? ((t + 1) & 1) : ((t - 1) & 1);

            // 1. poll own 128-word range (all complete before any publish)
            const u64* src = pt + (size_t)spar * 1024 + 128 * g;
            u64 a0, a1; bool d0 = false, d1 = false;
            for (;;) {
                if (!d0) { a0 = ald64(src + lane);      d0 = pt_tag(a0) == tagw; }
                if (!d1) { a1 = ald64(src + 64 + lane); d1 = pt_tag(a1) == tagw; }
                if (__all(d0 && d1)) break;
            }

            u64* dst = pt + (size_t)(t & 1) * 1024;
            if (act) {
                // 2. redistribute within wave via LDS
                pldL[lane]      = pt_val(a0);
                pldL[lane + 64] = pt_val(a1);
                // 3. ensure tile staged (normally already true)
                while (__hip_atomic_load(&readyCtr, __ATOMIC_RELAXED,
                                         __HIP_MEMORY_SCOPE_WORKGROUP) < 7 * (gen + 1)) {}
                asm volatile("" ::: "memory");
                LGKM0_FENCE();
                // 4. compute 2 outputs (exp pre-applied by staging)
                const float* e0 = &sm[buf][o0 * TSTR];
                const float* e1 = &sm[buf][o1 * TSTR];
                const float* p0 = &pldL[p0off];
                const float* p1 = &pldL[p1off];
                float acc0 = 0.f, acc1 = 0.f;
                #pragma unroll
                for (int m = 0; m < 32; ++m) {
                    acc0 = fmaf(e0[m], p0[m], acc0);
                    acc1 = fmaf(e1[m], p1[m], acc1);
                }
                last0 = acc0; last1 = acc1;
                ast64(dst + w0own, pt_pack(t, acc0));
                ast64(dst + w1own, pt_pack(t, acc1));
            } else {
                ast64(dst + w0own, pt_pack(t, last0));
                ast64(dst + w1own, pt_pack(t, last1));
            }
            // 5. release ring slot (after compute reads drained)
            LGKM0_FENCE();
            if (lane == 0)
                __hip_atomic_store(&doneGen, gen, __ATOMIC_RELAXED,
                                   __HIP_MEMORY_SCOPE_WORKGROUP);
        }
    }
}

// ---------------------------------------------------------------------------
// Kernel 4: finalize. Q_64 = ptF parity0 (tag 64); R_64 = ptB parity1 (tag 65).
// z_b = 4*cnt_b + log( sum Q_64 o R_64 ).
// ---------------------------------------------------------------------------
__global__ __launch_bounds__(1024) void finalize_dfb(const float* __restrict__ ws,
                                                     const u64*  __restrict__ ptF,
                                                     const u64*  __restrict__ ptB,
                                                     const int*  __restrict__ mask,
                                                     float*      __restrict__ out) {
    __shared__ float zs[32];
    const int w = threadIdx.x >> 6, lane = threadIdx.x & 63;
    for (int rep = 0; rep < 2; ++rep) {
        const int b = w + rep * 16;
        const u64* qf = ptF + (size_t)b * 2048;          // parity0, [k*32+j]
        const u64* rb = ptB + (size_t)b * 2048 + 1024;   // parity1, [i*32+j]
        float dot = 0.f;
        #pragma unroll
        for (int e = 0; e < 16; ++e) {
            const int x = lane + 64 * e;                 // x = k*32 + j
            dot += pt_val(qf[x]) * pt_val(rb[(x & 31) * 32 + (x >> 5)]);
        }
        float cnt = 0.f;
        {
            int t = 2 + lane;
            if (t < SEQ_LEN) cnt += (mask[t*BATCH + b] != 0) ? 1.f : 0.f;
            t += 64;
            if (t < SEQ_LEN) cnt += (mask[t*BATCH + b] != 0) ? 1.f : 0.f;
        }
        #pragma unroll
        for (int off = 32; off > 0; off >>= 1) {
            dot += __shfl_xor(dot, off, 64);
            cnt += __shfl_xor(cnt, off, 64);
        }
        if (lane == 0) zs[b] = 4.0f * cnt + logf(dot);
    }
    __syncthreads();
    if (threadIdx.x == 0) {
        float tg = 0.f, z = 0.f;
        #pragma unroll
        for (int i = 0; i < 16; ++i) tg += ws[i];
        #pragma unroll
        for (int i = 0; i < 32; ++i) z += zs[i];
        out[0] = (z - tg) / (float)BATCH;
    }
}

// ---------------------------------------------------------------------------
// Fallback (small ws): round-5 single-block-per-batch scan.
// ---------------------------------------------------------------------------
__global__ __launch_bounds__(1024) void scan_fast(const float* __restrict__ scores,
                                                  const int*   __restrict__ maskI,
                                                  float*       __restrict__ ws) {
    const int b    = blockIdx.x;
    const int tid  = threadIdx.x;
    const int w    = tid >> 6;
    const int lane = tid & 63;
    const int h    = lane >> 4;
    const int jp   = (lane >> 3) & 1;
    const int k4   = lane & 7;
    const int j    = w * 2 + jp;

    __shared__ float Q[2][TT];
    __shared__ int   lmask[SEQ_LEN];
    if (tid < SEQ_LEN) lmask[tid] = maskI[tid * BATCH + b];
    {
        int x = tid >> 5, y = tid & 31;
        float p1 = scores[(size_t)(0*BATCH + b)*TTT + START*TT + START*T + x];
        float s1 = scores[(size_t)(1*BATCH + b)*TTT + START*TT + x*T + y];
        Q[1][x*T + y] = __expf(p1 + s1);
    }
    __syncthreads();
    const int loff = h*8*TT + j*T + k4*4;
    float4 SA[8], SB[8];
    auto issue = [&](float4 (&S)[8], int t) {
        const float* p = scores + ((size_t)t*BATCH + b)*TTT + loff;
        #pragma unroll
        for (int m = 0; m < 8; ++m) S[m] = *(const float4*)(p + m*TT);
    };
    auto process = [&](float4 (&S)[8], int t) {
        const float* qc = Q[(t-1) & 1];
        float*       qn = Q[t & 1];
        #pragma unroll
        for (int m = 0; m < 8; ++m) {
            S[m].x = exp2f(fmaf(S[m].x, LOG2E, -OFF4));
            S[m].y = exp2f(fmaf(S[m].y, LOG2E, -OFF4));
            S[m].z = exp2f(fmaf(S[m].z, LOG2E, -OFF4));
            S[m].w = exp2f(fmaf(S[m].w, LOG2E, -OFF4));
        }
        float4 acc = make_float4(0.f, 0.f, 0.f, 0.f);
        #pragma unroll
        for (int m = 0; m < 8; ++m) {
            float q = qc[(h*8 + m)*T + j];
            acc.x = fmaf(S[m].x, q, acc.x);
            acc.y = fmaf(S[m].y, q, acc.y);
            acc.z = fmaf(S[m].z, q, acc.z);
            acc.w = fmaf(S[m].w, q, acc.w);
        }
        acc.x += __shfl_xor(acc.x, 16, 64); acc.y += __shfl_xor(acc.y, 16, 64);
        acc.z += __shfl_xor(acc.z, 16, 64); acc.w += __shfl_xor(acc.w, 16, 64);
        acc.x += __shfl_xor(acc.x, 32, 64); acc.y += __shfl_xor(acc.y, 32, 64);
        acc.z += __shfl_xor(acc.z, 32, 64); acc.w += __shfl_xor(acc.w, 32, 64);
        if (lane < 16) {
            if (lmask[t] != 0) *(float4*)&qn[j*T + k4*4] = acc;
            else               *(float4*)&qn[j*T + k4*4] = *(const float4*)&qc[j*T + k4*4];
        }
        asm volatile("s_waitcnt lgkmcnt(0)" ::: "memory");
        __builtin_amdgcn_s_barrier();
    };
    issue(SA, 2);
    for (int t = 2; t < SEQ_LEN; t += 2) {
        issue(SB, t + 1);
        process(SA, t);
        if (t + 2 < SEQ_LEN) issue(SA, t + 2);
        process(SB, t + 1);
    }
    if (tid == 0) {
        int cnt = 0;
        for (int t = 2; t < SEQ_LEN; ++t) cnt += (lmask[t] != 0);
        ws[16 + b] = 4.0f * (float)cnt + logf(Q[1][END*T + END]);
    }
}

__global__ void finalize_simple(const float* __restrict__ ws, float* __restrict__ out) {
    if (threadIdx.x == 0) {
        float tg = 0.f, z = 0.f;
        #pragma unroll
        for (int i = 0; i < 16; ++i) tg += ws[i];
        #pragma unroll
        for (int i = 0; i < 32; ++i) z += ws[16 + i];
        out[0] = (z - tg) / (float)BATCH;
    }
}

extern "C" void kernel_launch(void* const* d_in, const int* in_sizes, int n_in,
                              void* d_out, int out_size, void* d_ws, size_t ws_size,
                              hipStream_t stream) {
    const float* scores = (const float*)d_in[0];
    const int*   target = (const int*)d_in[1];
    const int*   mask   = (const int*)d_in[2];
    float* out = (float*)d_out;
    float* ws  = (float*)d_ws;
    u64*   ptF = (u64*)((char*)d_ws + 1024);
    u64*   ptB = ptF + (size_t)BATCH * 2048;
    const size_t need = 1024 + (size_t)2 * BATCH * 2048 * sizeof(u64);   // ~1.05 MB

    tg_kernel<<<16, 256, 0, stream>>>(scores, target, mask, ws);
    if (ws_size >= need) {
        init_dfb<<<2*BATCH, 256, 0, stream>>>(scores, ptF, ptB);
        scan_w0<<<512, 512, 0, stream>>>(scores, mask, ptF, ptB);
        finalize_dfb<<<1, 1024, 0, stream>>>(ws, ptF, ptB, mask, out);
    } else {
        scan_fast<<<BATCH, 1024, 0, stream>>>(scores, mask, ws);
        finalize_simple<<<1, 64, 0, stream>>>(ws, out);
    }
}